// Round 27
// baseline (27.999 us; speedup 1.0000x reference)
//
#include <hip/hip_runtime.h>

// DivEncLayer via MFMA — r17 staging/pipeline + MERGED-HALF finish (no defer).
// Per (b,q): h = elu(x[b,q*8:+8]@W1[q] + b1[q]); LN(h); out = h@W2[q]+b2[q].
// B=16384, Q=128, S=8, U=32.
//
// r21 bundled {merge, cross-iter deferral} and regressed; deferral's +6
// carried VGPRs is the suspected culprit (r3/r25 register-pressure pattern).
// This isolates the merge: per iter per wave 3 shfl (was 6), 1 epilogue
// (was 2), 1 branch-free lout write (was 2 predicated). Semantics proven by
// r21's PASS (absmax 0.03125): lane ln's output row is b0+ln — lanes<32
// keep tile A's partials, lanes>=32 keep tile B's; each sends the other
// tile's partial across the half boundary. Same addends, same order ->
// bit-identical results.
//
// v_mfma_f32_32x32x16_bf16 mapping (HW-validated r2-r11):
//   A: lane l, reg j -> A[l&31][j+8*(l>>5)]  B: lane l, reg j -> B[j+8*(l>>5)][l&31]
//   D: lane l, reg r -> row u=(r&3)+8*(r>>2)+4*(l>>5), col b=l&31
// Packed A-frag: lanes<32 = bf16(W1^T) (k<8), lanes>=32 = bf16(W1-whi) (k>=8).
// B-frag: staged bf16 panel row (halves dup) -> one ds_read_b128.
// D = (whi+wlo)*x_bf16 + b1 (C-in fp32). LN+Dense2 folded:
//   out = rsqrt(var+eps)*(dot(e,g2) - mu*G) + C.
// Staging: 3-deep ring, loads 2 iters ahead, lgkmcnt-only barriers (global
// loads stay in flight). Block = 4 waves = q-tile; 8 iters x 64 rows;
// grid (32,32). lout gather -> float4 stores (write-exact).

typedef __attribute__((ext_vector_type(8))) short short8;    // 8 bf16
typedef __attribute__((ext_vector_type(16))) float f32x16;

#define XS_STRIDE 40   // shorts per staged row (80 B): b128-aligned, 0-conflict

__device__ __forceinline__ short fbits(__bf16 b) { return __builtin_bit_cast(short, b); }

__device__ __forceinline__ float elu1(float v) {
    return v > 0.f ? v : __expf(v) - 1.f;
}

__device__ __forceinline__ short4 cvt4(float4 v) {
    short4 r;
    r.x = fbits((__bf16)v.x); r.y = fbits((__bf16)v.y);
    r.z = fbits((__bf16)v.z); r.w = fbits((__bf16)v.w);
    return r;
}

// barrier WITHOUT vmcnt drain: DS visibility only, global loads stay in flight
__device__ __forceinline__ void barrier_ds_only() {
    asm volatile("s_waitcnt lgkmcnt(0)" ::: "memory");
    __builtin_amdgcn_s_barrier();
}

__global__ __launch_bounds__(256, 4) void divenc_mfma(
    const float* __restrict__ x,      // (16384, 1024)
    const float* __restrict__ W1,     // (128, 8, 32)
    const float* __restrict__ b1,     // (128, 32)
    const float* __restrict__ gamma,  // (128, 32)
    const float* __restrict__ beta,   // (128, 32)
    const float* __restrict__ W2,     // (128, 32)
    const float* __restrict__ b2,     // (128,)
    float* __restrict__ out)          // (16384, 128)
{
    __shared__ short xs[3][64 * XS_STRIDE];   // 3-deep staged bf16 panels (15 KB)
    __shared__ float lout[512 * 5];           // results, padded stride 5 (10 KB)

    const int tid  = threadIdx.x;
    const int w    = tid >> 6;
    const int ln   = tid & 63;
    const int u    = ln & 31;
    const int half = ln >> 5;
    const int qt   = blockIdx.y;      // 0..31
    const int q    = qt * 4 + w;
    const int bx   = blockIdx.x;      // 0..31; band = rows bx*512..+511
    const int band = bx * 512;

    // staging role: 8 threads cover one 128B row; thread t does rows t>>3, +32
    const int srow0 = tid >> 3;
    const int srow1 = srow0 + 32;
    const int schk  = tid & 7;
    const float* xpan = x + qt * 32 + schk * 4;

    // ---- A-frag: lanes<32 = whi (k=0..7), lanes>=32 = wlo (k=8..15) ----
    short8 wfrag;
    #pragma unroll
    for (int j = 0; j < 8; ++j) {
        float f  = W1[q * 256 + j * 32 + u];
        __bf16 h = (__bf16)f;
        wfrag[j] = half ? fbits((__bf16)(f - (float)h)) : fbits(h);
    }

    // ---- params: biasr (MFMA C-in) + g2r in regs, vector loads ----
    f32x16 biasr, g2r;
    float G, C;
    {
        float gs = 0.f, cs = 0.f;
        #pragma unroll
        for (int c = 0; c < 4; ++c) {
            const int ub = q * 32 + 4 * half + 8 * c;
            float4 b1v = *(const float4*)&b1[ub];
            float4 gav = *(const float4*)&gamma[ub];
            float4 w2v = *(const float4*)&W2[ub];
            float4 bev = *(const float4*)&beta[ub];
            #pragma unroll
            for (int j = 0; j < 4; ++j) {
                float g2 = ((const float*)&gav)[j] * ((const float*)&w2v)[j];
                biasr[4 * c + j] = ((const float*)&b1v)[j];
                g2r[4 * c + j]   = g2;
                gs += g2;
                cs += ((const float*)&bev)[j] * ((const float*)&w2v)[j];
            }
        }
        gs += __shfl_xor(gs, 32);   // halves hold complementary u-sets
        cs += __shfl_xor(cs, 32);
        G = gs;
        C = cs + b2[q];
    }

    // ---- prologue: stage panel 0; issue panel 1's loads (stay in flight) ----
    {
        float4 g0 = *(const float4*)(xpan + (size_t)(band + srow0) * 1024);
        float4 g1 = *(const float4*)(xpan + (size_t)(band + srow1) * 1024);
        *(short4*)&xs[0][srow0 * XS_STRIDE + schk * 4] = cvt4(g0);
        *(short4*)&xs[0][srow1 * XS_STRIDE + schk * 4] = cvt4(g1);
    }
    float4 p0 = *(const float4*)(xpan + (size_t)(band + 64 + srow0) * 1024);
    float4 p1 = *(const float4*)(xpan + (size_t)(band + 64 + srow1) * 1024);
    barrier_ds_only();

    #pragma unroll 1
    for (int it = 0; it < 8; ++it) {
        const int cur = it % 3;
        const int nxt = (it + 1) % 3;
        const int b0  = it * 64;        // row offset within band

        // issue loads for panel it+2 (2 iterations ahead; stay in flight)
        float4 f0, f1;
        if (it < 6) {
            f0 = *(const float4*)(xpan + (size_t)(band + b0 + 128 + srow0) * 1024);
            f1 = *(const float4*)(xpan + (size_t)(band + b0 + 128 + srow1) * 1024);
        }

        // ---- compute on panel cur ----
        short8 xa = *(const short8*)&xs[cur][u * XS_STRIDE + w * 8];
        short8 xb = *(const short8*)&xs[cur][(u + 32) * XS_STRIDE + w * 8];

        f32x16 accA = __builtin_amdgcn_mfma_f32_32x32x16_bf16(wfrag, xa, biasr, 0, 0, 0);
        f32x16 accB = __builtin_amdgcn_mfma_f32_32x32x16_bf16(wfrag, xb, biasr, 0, 0, 0);

        // ---- merged-half finish: partials for BOTH tiles ----
        float sA = 0.f, qA = 0.f, dA = 0.f;
        float sB = 0.f, qB = 0.f, dB = 0.f;
        #pragma unroll
        for (int r = 0; r < 16; ++r) {
            float eA = elu1(accA[r]);
            float eB = elu1(accB[r]);
            sA += eA;                    sB += eB;
            qA = fmaf(eA, eA, qA);       qB = fmaf(eB, eB, qB);
            dA = fmaf(eA, g2r[r], dA);   dB = fmaf(eB, g2r[r], dB);
        }
        // keep own tile (A for lanes<32, B for lanes>=32); send the other.
        // tot = keep(local half) + shfl(send, 32)(remote half) — same addend
        // order as r17's per-tile reduce -> bit-identical results.
        float ks = half ? sB : sA, es = half ? sA : sB;
        float kq = half ? qB : qA, eq = half ? qA : qB;
        float kd = half ? dB : dA, ed = half ? dA : dB;
        float ts = ks + __shfl_xor(es, 32);
        float tq = kq + __shfl_xor(eq, 32);
        float td = kd + __shfl_xor(ed, 32);
        float mu  = ts * 0.03125f;
        float var = fmaf(-mu, mu, tq * 0.03125f);
        float inv = rsqrtf(var + 1e-3f);
        float res = fmaf(inv, fmaf(-mu, G, td), C);
        lout[(b0 + ln) * 5 + w] = res;   // branch-free: lane ln owns row b0+ln

        // ---- write panel it+1 from pending regs (vmcnt counted, not drained) ----
        if (it < 7) {
            *(short4*)&xs[nxt][srow0 * XS_STRIDE + schk * 4] = cvt4(p0);
            *(short4*)&xs[nxt][srow1 * XS_STRIDE + schk * 4] = cvt4(p1);
            barrier_ds_only();   // DS visibility only; vmcnt NOT drained
        }

        p0 = f0;
        p1 = f1;
    }

    __syncthreads();   // final full barrier before the gather

    // ---- gather/store: 512 rows, 2 per thread, float4 each (write-exact) ----
    {
        const int r0 = tid;
        const int r1 = tid + 256;
        float4 o0, o1;
        o0.x = lout[r0 * 5 + 0]; o0.y = lout[r0 * 5 + 1];
        o0.z = lout[r0 * 5 + 2]; o0.w = lout[r0 * 5 + 3];
        o1.x = lout[r1 * 5 + 0]; o1.y = lout[r1 * 5 + 1];
        o1.z = lout[r1 * 5 + 2]; o1.w = lout[r1 * 5 + 3];
        *(float4*)(out + (size_t)(band + r0) * 128 + qt * 4) = o0;
        *(float4*)(out + (size_t)(band + r1) * 128 + qt * 4) = o1;
    }
}

extern "C" void kernel_launch(void* const* d_in, const int* in_sizes, int n_in,
                              void* d_out, int out_size, void* d_ws, size_t ws_size,
                              hipStream_t stream) {
    const float* x     = (const float*)d_in[0];
    const float* W1    = (const float*)d_in[1];
    const float* b1    = (const float*)d_in[2];
    const float* gamma = (const float*)d_in[3];
    const float* beta  = (const float*)d_in[4];
    const float* W2    = (const float*)d_in[5];
    const float* b2    = (const float*)d_in[6];
    float* out = (float*)d_out;

    dim3 grid(32, 32);   // (512-row bands, q-tiles of 4)
    divenc_mfma<<<grid, 256, 0, stream>>>(x, W1, b1, gamma, beta, W2, b2, out);
}

// Round 28
// 27.596 us; speedup vs baseline: 1.0146x; 1.0146x over previous
//
#include <hip/hip_runtime.h>

// DivEncLayer via MFMA — FINAL (r17 configuration; best measured 27.59-27.78us,
// confirmed x3). Per (b,q): h = elu(x[b,q*8:+8]@W1[q] + b1[q]); LN(h);
// out = h@W2[q]+b2[q].  B=16384, Q=128, S=8, U=32.
//
// Survivors of 27 rounds of theory->edit->measure:
//  - ONE v_mfma_f32_32x32x16_bf16 per 32-row tile: packed hi/lo A-frag
//    (lanes<32 = bf16(W1^T) in k<8, lanes>=32 = bf16(W1-whi) in k>=8); B dups
//    each row across lane-halves -> D = (whi+wlo)*x_bf16 + b1 (C-in, fp32).
//  - LN+Dense2 folded: out = rsqrt(var+eps)*(dot(e,g2) - mu*G) + C.
//  - Block-cooperative coalesced staging (8 thr per 128B x-row, float4),
//    bf16 panels at 80B pitch (0 bank conflicts).  [r11: +1.2us]
//  - 3-deep panel ring, loads 2 iters ahead, barriers = lgkmcnt(0)+s_barrier
//    only (no vmcnt drain -> loads stay in flight).   [r17: +1.0us]
//  - Padded-LDS result gather -> one float4 store per row (write-exact).
// Refuted (null/negative, each isolated): TLP reshaping, multi-chain ILP,
// zero-barrier loops, depth-2/4 prefetch, global_load_lds + counted vmcnt,
// producer/consumer waves, deferred epilogues (LDS & reg), packed-f32 math,
// merged-half finish (r27), wave-private panels, start stagger, 8-wave
// chain-halving.
// Plateau analysis: staging ~10us (L3-fabric-bound: x is L3-resident, 72MB
// logical / 9.8us ≈ 7.3TB/s) + compute ~15us (VALU issue + chain latency),
// additive at HIP level for this dependency shape. Fusing the phases needs
// instruction-level schedule control (hand-asm interleave), beyond HIP source.
//
// v_mfma_f32_32x32x16_bf16 mapping (HW-validated in-loop r2-r11):
//   A: lane l, reg j -> A[l&31][j+8*(l>>5)]  B: lane l, reg j -> B[j+8*(l>>5)][l&31]
//   D: lane l, reg r -> row u=(r&3)+8*(r>>2)+4*(l>>5), col b=l&31
// Block = 4 waves = q-tile (wave w owns q=qt*4+w); 8 iters x 64 rows =
// 512-row band; grid (32,32) = 1024 blocks.

typedef __attribute__((ext_vector_type(8))) short short8;    // 8 bf16
typedef __attribute__((ext_vector_type(16))) float f32x16;

#define XS_STRIDE 40   // shorts per staged row (80 B): b128-aligned, 0-conflict

__device__ __forceinline__ short fbits(__bf16 b) { return __builtin_bit_cast(short, b); }

__device__ __forceinline__ float elu1(float v) {
    return v > 0.f ? v : __expf(v) - 1.f;
}

__device__ __forceinline__ short4 cvt4(float4 v) {
    short4 r;
    r.x = fbits((__bf16)v.x); r.y = fbits((__bf16)v.y);
    r.z = fbits((__bf16)v.z); r.w = fbits((__bf16)v.w);
    return r;
}

// barrier WITHOUT vmcnt drain: DS visibility only, global loads stay in flight
__device__ __forceinline__ void barrier_ds_only() {
    asm volatile("s_waitcnt lgkmcnt(0)" ::: "memory");
    __builtin_amdgcn_s_barrier();
}

__global__ __launch_bounds__(256, 4) void divenc_mfma(
    const float* __restrict__ x,      // (16384, 1024)
    const float* __restrict__ W1,     // (128, 8, 32)
    const float* __restrict__ b1,     // (128, 32)
    const float* __restrict__ gamma,  // (128, 32)
    const float* __restrict__ beta,   // (128, 32)
    const float* __restrict__ W2,     // (128, 32)
    const float* __restrict__ b2,     // (128,)
    float* __restrict__ out)          // (16384, 128)
{
    __shared__ short xs[3][64 * XS_STRIDE];   // 3-deep staged bf16 panels (15 KB)
    __shared__ float lout[512 * 5];           // results, padded stride 5 (10 KB)

    const int tid  = threadIdx.x;
    const int w    = tid >> 6;
    const int ln   = tid & 63;
    const int u    = ln & 31;
    const int half = ln >> 5;
    const int qt   = blockIdx.y;      // 0..31
    const int q    = qt * 4 + w;
    const int bx   = blockIdx.x;      // 0..31; band = rows bx*512..+511
    const int band = bx * 512;

    // staging role: 8 threads cover one 128B row; thread t does rows t>>3, +32
    const int srow0 = tid >> 3;
    const int srow1 = srow0 + 32;
    const int schk  = tid & 7;
    const float* xpan = x + qt * 32 + schk * 4;

    // ---- A-frag: lanes<32 = whi (k=0..7), lanes>=32 = wlo (k=8..15) ----
    short8 wfrag;
    #pragma unroll
    for (int j = 0; j < 8; ++j) {
        float f  = W1[q * 256 + j * 32 + u];
        __bf16 h = (__bf16)f;
        wfrag[j] = half ? fbits((__bf16)(f - (float)h)) : fbits(h);
    }

    // ---- params: biasr (MFMA C-in) + g2r in regs, vector loads ----
    f32x16 biasr, g2r;
    float G, C;
    {
        float gs = 0.f, cs = 0.f;
        #pragma unroll
        for (int c = 0; c < 4; ++c) {
            const int ub = q * 32 + 4 * half + 8 * c;
            float4 b1v = *(const float4*)&b1[ub];
            float4 gav = *(const float4*)&gamma[ub];
            float4 w2v = *(const float4*)&W2[ub];
            float4 bev = *(const float4*)&beta[ub];
            #pragma unroll
            for (int j = 0; j < 4; ++j) {
                float g2 = ((const float*)&gav)[j] * ((const float*)&w2v)[j];
                biasr[4 * c + j] = ((const float*)&b1v)[j];
                g2r[4 * c + j]   = g2;
                gs += g2;
                cs += ((const float*)&bev)[j] * ((const float*)&w2v)[j];
            }
        }
        gs += __shfl_xor(gs, 32);   // halves hold complementary u-sets
        cs += __shfl_xor(cs, 32);
        G = gs;
        C = cs + b2[q];
    }

    // ---- prologue: stage panel 0; issue panel 1's loads (stay in flight) ----
    {
        float4 g0 = *(const float4*)(xpan + (size_t)(band + srow0) * 1024);
        float4 g1 = *(const float4*)(xpan + (size_t)(band + srow1) * 1024);
        *(short4*)&xs[0][srow0 * XS_STRIDE + schk * 4] = cvt4(g0);
        *(short4*)&xs[0][srow1 * XS_STRIDE + schk * 4] = cvt4(g1);
    }
    float4 p0 = *(const float4*)(xpan + (size_t)(band + 64 + srow0) * 1024);
    float4 p1 = *(const float4*)(xpan + (size_t)(band + 64 + srow1) * 1024);
    barrier_ds_only();

    #pragma unroll 1
    for (int it = 0; it < 8; ++it) {
        const int cur = it % 3;
        const int nxt = (it + 1) % 3;
        const int b0  = it * 64;        // row offset within band

        // issue loads for panel it+2 (2 iterations ahead; stay in flight)
        float4 f0, f1;
        if (it < 6) {
            f0 = *(const float4*)(xpan + (size_t)(band + b0 + 128 + srow0) * 1024);
            f1 = *(const float4*)(xpan + (size_t)(band + b0 + 128 + srow1) * 1024);
        }

        // ---- compute on panel cur ----
        short8 xa = *(const short8*)&xs[cur][u * XS_STRIDE + w * 8];
        short8 xb = *(const short8*)&xs[cur][(u + 32) * XS_STRIDE + w * 8];

        f32x16 accA = __builtin_amdgcn_mfma_f32_32x32x16_bf16(wfrag, xa, biasr, 0, 0, 0);
        f32x16 accB = __builtin_amdgcn_mfma_f32_32x32x16_bf16(wfrag, xb, biasr, 0, 0, 0);

        {
            float sum = 0.f, ss = 0.f, dot = 0.f;
            #pragma unroll
            for (int r = 0; r < 16; ++r) {
                float e = elu1(accA[r]);
                sum += e;
                ss  = fmaf(e, e, ss);
                dot = fmaf(e, g2r[r], dot);
            }
            sum += __shfl_xor(sum, 32);
            ss  += __shfl_xor(ss, 32);
            dot += __shfl_xor(dot, 32);
            float mu  = sum * 0.03125f;
            float var = fmaf(-mu, mu, ss * 0.03125f);
            float inv = rsqrtf(var + 1e-3f);
            float res = fmaf(inv, fmaf(-mu, G, dot), C);
            if (half == 0) lout[(b0 + u) * 5 + w] = res;
        }
        {
            float sum = 0.f, ss = 0.f, dot = 0.f;
            #pragma unroll
            for (int r = 0; r < 16; ++r) {
                float e = elu1(accB[r]);
                sum += e;
                ss  = fmaf(e, e, ss);
                dot = fmaf(e, g2r[r], dot);
            }
            sum += __shfl_xor(sum, 32);
            ss  += __shfl_xor(ss, 32);
            dot += __shfl_xor(dot, 32);
            float mu  = sum * 0.03125f;
            float var = fmaf(-mu, mu, ss * 0.03125f);
            float inv = rsqrtf(var + 1e-3f);
            float res = fmaf(inv, fmaf(-mu, G, dot), C);
            if (half == 0) lout[(b0 + 32 + u) * 5 + w] = res;
        }

        // ---- write panel it+1 from pending regs (vmcnt counted, not drained) ----
        if (it < 7) {
            *(short4*)&xs[nxt][srow0 * XS_STRIDE + schk * 4] = cvt4(p0);
            *(short4*)&xs[nxt][srow1 * XS_STRIDE + schk * 4] = cvt4(p1);
            barrier_ds_only();   // DS visibility only; vmcnt NOT drained
        }

        p0 = f0;
        p1 = f1;
    }

    __syncthreads();   // final full barrier before the gather

    // ---- gather/store: 512 rows, 2 per thread, float4 each (write-exact) ----
    {
        const int r0 = tid;
        const int r1 = tid + 256;
        float4 o0, o1;
        o0.x = lout[r0 * 5 + 0]; o0.y = lout[r0 * 5 + 1];
        o0.z = lout[r0 * 5 + 2]; o0.w = lout[r0 * 5 + 3];
        o1.x = lout[r1 * 5 + 0]; o1.y = lout[r1 * 5 + 1];
        o1.z = lout[r1 * 5 + 2]; o1.w = lout[r1 * 5 + 3];
        *(float4*)(out + (size_t)(band + r0) * 128 + qt * 4) = o0;
        *(float4*)(out + (size_t)(band + r1) * 128 + qt * 4) = o1;
    }
}

extern "C" void kernel_launch(void* const* d_in, const int* in_sizes, int n_in,
                              void* d_out, int out_size, void* d_ws, size_t ws_size,
                              hipStream_t stream) {
    const float* x     = (const float*)d_in[0];
    const float* W1    = (const float*)d_in[1];
    const float* b1    = (const float*)d_in[2];
    const float* gamma = (const float*)d_in[3];
    const float* beta  = (const float*)d_in[4];
    const float* W2    = (const float*)d_in[5];
    const float* b2    = (const float*)d_in[6];
    float* out = (float*)d_out;

    dim3 grid(32, 32);   // (512-row bands, q-tiles of 4)
    divenc_mfma<<<grid, 256, 0, stream>>>(x, W1, b1, gamma, beta, W2, b2, out);
}